// Round 11
// baseline (361.846 us; speedup 1.0000x reference)
//
#include <hip/hip_runtime.h>
#include <hip/hip_bf16.h>
#include <math.h>

// Problem constants
#define BB 4
#define NN 1024
#define DD 256
#define CC 8
#define KNBR 16
#define MAXSEL 17   // 16 top-k + possibly the diagonal
#define ZCAP (NN * MAXSEL)   // 17408 max CSR entries per b (structure shared by 8 channels)

typedef _Float16 f16x8_t __attribute__((ext_vector_type(8)));
typedef _Float16 f16x4_t __attribute__((ext_vector_type(4)));
typedef _Float16 f16x2_t __attribute__((ext_vector_type(2)));
typedef float    f32x4_t __attribute__((ext_vector_type(4)));

// async global->LDS, 16 bytes per lane. ldsbase must be wave-uniform
// (HW places lane i at ldsbase + i*16).
__device__ __forceinline__ void gl2lds16(const _Float16* g, _Float16* ldsbase) {
    __builtin_amdgcn_global_load_lds(
        (const __attribute__((address_space(1))) unsigned int*)g,
        (__attribute__((address_space(3))) unsigned int*)ldsbase, 16, 0, 0);
}

// 2-level fp16 split: v = h + l + eps, |eps| <= ~2^-23 |v|
__device__ __forceinline__ void split2(float v, _Float16& h, _Float16& l) {
    h = (_Float16)v;
    l = (_Float16)(v - (float)h);
}

// ---------------------------------------------------------------------------
// Kernel 0: fused input prep. Blocks 0..1023: split x (fp16 h+l).
// Blocks 1024..1279: transpose + split 16*W (scale keeps residuals out of
// fp16 subnormal range; compensated by qkt scale /256).
// Block 1024 also zeroes countb.
// ---------------------------------------------------------------------------
__global__ __launch_bounds__(256) void split_all(const float* __restrict__ x,
                                                 const float* __restrict__ W,
                                                 _Float16* __restrict__ xh,
                                                 _Float16* __restrict__ xl,
                                                 _Float16* __restrict__ Wth,
                                                 _Float16* __restrict__ Wtl,
                                                 int* __restrict__ countb) {
    const int tid = threadIdx.x;
    if (blockIdx.x < 1024) {
        int i = (blockIdx.x * 256 + tid) * 4;
        float4 v = *(const float4*)(x + i);
        f16x4_t hv, lv;
        _Float16 h, l;
        split2(v.x, h, l); hv[0] = h; lv[0] = l;
        split2(v.y, h, l); hv[1] = h; lv[1] = l;
        split2(v.z, h, l); hv[2] = h; lv[2] = l;
        split2(v.w, h, l); hv[3] = h; lv[3] = l;
        *(f16x4_t*)(xh + i) = hv;
        *(f16x4_t*)(xl + i) = lv;
    } else {
        const int b2 = blockIdx.x - 1024;
        if (b2 == 0) {
            int4 zz = make_int4(0, 0, 0, 0);
#pragma unroll
            for (int g = 0; g < 4; g++) ((int4*)countb)[tid + 256 * g] = zz;
        }
        __shared__ float t[64][65];
        const int n0 = (b2 & 63) * 64;
        const int k0 = (b2 >> 6) * 64;
#pragma unroll
        for (int i = 0; i < 16; i++) {
            int k = i * 4 + (tid >> 6);
            int n = tid & 63;
            t[k][n] = W[(size_t)(k0 + k) * 4096 + n0 + n];
        }
        __syncthreads();
#pragma unroll
        for (int i = 0; i < 16; i++) {
            int n = i * 4 + (tid >> 6);
            int k = tid & 63;
            _Float16 h, l;
            split2(t[k][n] * 16.f, h, l);
            size_t o = (size_t)(n0 + n) * 256 + k0 + k;
            Wth[o] = h; Wtl[o] = l;
        }
    }
}

// stage one 128x32 fp16 tile (see R1 swizzle comment).
#define STG(dst, src, rowbase, kk)                                             \
    do {                                                                       \
        gl2lds16((src) + (size_t)((rowbase) + r_st) * 256 + (kk) + c8,         \
                 &(dst)[(w * 64) * 8]);                                        \
        gl2lds16((src) + (size_t)((rowbase) + 64 + r_st) * 256 + (kk) + c8,    \
                 &(dst)[(256 + w * 64) * 8]);                                  \
    } while (0)

// 3-term product ladder (hh last). (ah+al)(bh+bl) ~ al*bh + ah*bl + ah*bh
#define MFMA3(accv, AH, AL, BH, BL)                                            \
    do {                                                                       \
        accv = __builtin_amdgcn_mfma_f32_16x16x32_f16(AL, BH, accv, 0, 0, 0);  \
        accv = __builtin_amdgcn_mfma_f32_16x16x32_f16(AH, BL, accv, 0, 0, 0);  \
        accv = __builtin_amdgcn_mfma_f32_16x16x32_f16(AH, BH, accv, 0, 0, 0);  \
    } while (0)

// fragment loads + MFMA for one staged K=32 tile set
#define COMPUTE(AH, AL, BH, BL)                                                \
    do {                                                                       \
        f16x8_t ah[4], al[4];                                                  \
        _Pragma("unroll")                                                      \
        for (int mi = 0; mi < 4; mi++) {                                       \
            int r = (wr * 64 + mi * 16 + lm) * 32 + qx8;                       \
            ah[mi] = *(const f16x8_t*)&(AH)[r];                                \
            al[mi] = *(const f16x8_t*)&(AL)[r];                                \
        }                                                                      \
        _Pragma("unroll")                                                      \
        for (int ni = 0; ni < 4; ni++) {                                       \
            int rb = (wc * 64 + ni * 16 + lm) * 32 + qx8;                      \
            f16x8_t bh = *(const f16x8_t*)&(BH)[rb];                           \
            f16x8_t bl = *(const f16x8_t*)&(BL)[rb];                           \
            _Pragma("unroll")                                                  \
            for (int mi = 0; mi < 4; mi++)                                     \
                MFMA3(acc[mi][ni], ah[mi], al[mi], bh, bl);                    \
        }                                                                      \
    } while (0)

// ---------------------------------------------------------------------------
// Kernel 1: qk = x @ (16W) via 3-term fp16x2 MFMA, double-buffered LDS with
// next-tile prefetch (one barrier per K-iter); LDS-transpose epilogue with
// coalesced fp16x8 stores of the 2-split q/k components.
// ---------------------------------------------------------------------------
__global__ __launch_bounds__(256) void gemm_xw_mfma(
        const _Float16* __restrict__ xh, const _Float16* __restrict__ xl,
        const _Float16* __restrict__ wth, const _Float16* __restrict__ wtl,
        _Float16* __restrict__ qh, _Float16* __restrict__ ql,
        _Float16* __restrict__ kh, _Float16* __restrict__ kl) {
    __shared__ __align__(16) char smem[65536];
    _Float16* Ah0 = (_Float16*)smem;
    _Float16* Al0 = (_Float16*)(smem + 8192);
    _Float16* Bh0 = (_Float16*)(smem + 16384);
    _Float16* Bl0 = (_Float16*)(smem + 24576);
    _Float16* Ah1 = (_Float16*)(smem + 32768);
    _Float16* Al1 = (_Float16*)(smem + 40960);
    _Float16* Bh1 = (_Float16*)(smem + 49152);
    _Float16* Bl1 = (_Float16*)(smem + 57344);
    const int tid = threadIdx.x, lane = tid & 63, w = tid >> 6;
    const int wr = w >> 1, wc = w & 1;
    const int lm = lane & 15, quad = lane >> 4;
    const int row0 = blockIdx.y * 128, col0 = blockIdx.x * 128;
    const int r_st = tid >> 2;
    const int c8 = (((tid & 3) ^ ((tid >> 3) & 3)) * 8);
    const int qx8 = ((quad ^ ((lm >> 1) & 3)) * 8);

    f32x4_t acc[4][4];
#pragma unroll
    for (int i = 0; i < 4; i++)
#pragma unroll
        for (int j = 0; j < 4; j++) acc[i][j] = (f32x4_t)(0.f);

    STG(Ah0, xh, row0, 0); STG(Al0, xl, row0, 0);
    STG(Bh0, wth, col0, 0); STG(Bl0, wtl, col0, 0);
    __syncthreads();
#pragma unroll
    for (int t = 0; t < 8; t += 2) {
        {
            int kn = (t + 1) * 32;
            if (t + 1 < 8) {
                STG(Ah1, xh, row0, kn); STG(Al1, xl, row0, kn);
                STG(Bh1, wth, col0, kn); STG(Bl1, wtl, col0, kn);
            }
            COMPUTE(Ah0, Al0, Bh0, Bl0);
            __syncthreads();
        }
        {
            int kn = (t + 2) * 32;
            if (t + 2 < 8) {
                STG(Ah0, xh, row0, kn); STG(Al0, xl, row0, kn);
                STG(Bh0, wth, col0, kn); STG(Bl0, wtl, col0, kn);
            }
            COMPUTE(Ah1, Al1, Bh1, Bl1);
            __syncthreads();
        }
    }

    // Epilogue: two 64-row passes through LDS (fp32, stride 132 = bank-safe),
    // then coalesced fp16x8 stores of the 2 split components.
    float* tr = (float*)smem;   // 64 x 132 fp32 = 33792 B
    const int s = col0 >> 11, c = (col0 >> 8) & 7, dbase = col0 & 255;
    _Float16* dh = s ? kh : qh;
    _Float16* dl = s ? kl : ql;
    const int rl = tid >> 2;
    const int cb = (tid & 3) * 8;
#pragma unroll
    for (int p = 0; p < 2; p++) {
        if (p) __syncthreads();
        if (wr == p) {
#pragma unroll
            for (int mi = 0; mi < 4; mi++) {
                int rloc = mi * 16 + quad * 4;
#pragma unroll
                for (int ni = 0; ni < 4; ni++) {
                    int cl = wc * 64 + ni * 16 + lm;
#pragma unroll
                    for (int r = 0; r < 4; r++)
                        tr[(rloc + r) * 132 + cl] = acc[mi][ni][r];
                }
            }
        }
        __syncthreads();
        int rr = row0 + p * 64 + rl;
        int bb = rr >> 10, n = rr & 1023;
        size_t base = (((size_t)(bb * CC + c)) * NN + n) * DD + dbase;
#pragma unroll
        for (int g = 0; g < 4; g++) {
            int ccol = g * 32 + cb;
            f16x8_t hv, lv;
#pragma unroll
            for (int e = 0; e < 8; e++) {
                float vv = tr[rl * 132 + ccol + e];
                _Float16 h, l;
                split2(vv, h, l);
                hv[e] = h; lv[e] = l;
            }
            *(f16x8_t*)(dh + base + ccol) = hv;
            *(f16x8_t*)(dl + base + ccol) = lv;
        }
    }
}

// ---------------------------------------------------------------------------
// Kernel 2: per z: attn = (q @ k^T) * scale via 3-term fp16x2 MFMA,
// double-buffered LDS with next-tile prefetch. scale = 0.0625/256 (q,k carry
// 16x each from 16W). Grid swizzled so all 64 blocks of a z share one XCD.
// ---------------------------------------------------------------------------
__global__ __launch_bounds__(256) void gemm_qkt_mfma(
        const _Float16* __restrict__ qh, const _Float16* __restrict__ ql,
        const _Float16* __restrict__ kh, const _Float16* __restrict__ kl,
        float* __restrict__ attn) {
    __shared__ __align__(16) char smem[65536];
    _Float16* Ah0 = (_Float16*)smem;
    _Float16* Al0 = (_Float16*)(smem + 8192);
    _Float16* Bh0 = (_Float16*)(smem + 16384);
    _Float16* Bl0 = (_Float16*)(smem + 24576);
    _Float16* Ah1 = (_Float16*)(smem + 32768);
    _Float16* Al1 = (_Float16*)(smem + 40960);
    _Float16* Bh1 = (_Float16*)(smem + 49152);
    _Float16* Bl1 = (_Float16*)(smem + 57344);
    const int tid = threadIdx.x, lane = tid & 63, w = tid >> 6;
    const int wr = w >> 1, wc = w & 1;
    const int lm = lane & 15, quad = lane >> 4;
    const int id = blockIdx.x;
    const int rb8 = id & 7, qq = id >> 3;
    const int j = qq & 63, zhi = qq >> 6;
    const int z = zhi * 8 + rb8;
    const int row0 = (j >> 3) * 128, col0 = (j & 7) * 128;
    const size_t zo = (size_t)z * NN * DD;
    float* Cm = attn + (size_t)z * NN * NN;
    const int r_st = tid >> 2;
    const int c8 = (((tid & 3) ^ ((tid >> 3) & 3)) * 8);
    const int qx8 = ((quad ^ ((lm >> 1) & 3)) * 8);
    const float scale = 0.0625f / 256.0f;

    f32x4_t acc[4][4];
#pragma unroll
    for (int i = 0; i < 4; i++)
#pragma unroll
        for (int j2 = 0; j2 < 4; j2++) acc[i][j2] = (f32x4_t)(0.f);

    const _Float16* qhz = qh + zo;
    const _Float16* qlz = ql + zo;
    const _Float16* khz = kh + zo;
    const _Float16* klz = kl + zo;

    STG(Ah0, qhz, row0, 0); STG(Al0, qlz, row0, 0);
    STG(Bh0, khz, col0, 0); STG(Bl0, klz, col0, 0);
    __syncthreads();
#pragma unroll
    for (int t = 0; t < 8; t += 2) {
        {
            int kn = (t + 1) * 32;
            if (t + 1 < 8) {
                STG(Ah1, qhz, row0, kn); STG(Al1, qlz, row0, kn);
                STG(Bh1, khz, col0, kn); STG(Bl1, klz, col0, kn);
            }
            COMPUTE(Ah0, Al0, Bh0, Bl0);
            __syncthreads();
        }
        {
            int kn = (t + 2) * 32;
            if (t + 2 < 8) {
                STG(Ah0, qhz, row0, kn); STG(Al0, qlz, row0, kn);
                STG(Bh0, khz, col0, kn); STG(Bl0, klz, col0, kn);
            }
            COMPUTE(Ah1, Al1, Bh1, Bl1);
            __syncthreads();
        }
    }

#pragma unroll
    for (int mi = 0; mi < 4; mi++)
#pragma unroll
        for (int ni = 0; ni < 4; ni++) {
            int row = row0 + wr * 64 + mi * 16 + quad * 4;
            int col = col0 + wc * 64 + ni * 16 + lm;
#pragma unroll
            for (int r = 0; r < 4; r++)
                Cm[(size_t)(row + r) * NN + col] = acc[mi][ni][r] * scale;
        }
}

// ---------------------------------------------------------------------------
// Kernel 3: ONE ROW PER WAVE softmax+topk (R10 restructure). Each wave owns
// one (b,n): loads all 8 channels' 16-col slices upfront (32 float4 loads in
// flight), stats per channel via shfl_xor butterflies (identical reduction
// order to R9 -> bitwise-same results), channel-sum accumulated in REGISTERS
// (no psum LDS, no barriers). Threshold-select top-16 runs per wave (all 4
// waves busy; search range capped at 8.0). fsel is wave-private LDS scratch.
// ---------------------------------------------------------------------------
__global__ __launch_bounds__(256) void softmax_topk(const float* __restrict__ attn,
                                                    float2* __restrict__ ml,
                                                    int* __restrict__ idx,
                                                    int* __restrict__ cnt,
                                                    int* __restrict__ countb,
                                                    float* __restrict__ colsum) {
    __shared__ int fsel[4][MAXSEL];
    const int tid = threadIdx.x, lane = tid & 63, w = tid >> 6;
    const int bn = blockIdx.x * 4 + w;   // one row per wave
    const int b = bn >> 10, n = bn & 1023;

    if (lane < CC) colsum[(size_t)(b * CC + lane) * NN + n] = 0.f;

    const int colb = lane * 16;
    // all 8 channels loaded upfront: 32 float4 loads in flight, one latency
    float4 u[CC][4];
#pragma unroll
    for (int c = 0; c < CC; c++) {
        const float* rowp = attn + (((size_t)(b * CC + c) * NN + n) * NN) + colb;
#pragma unroll
        for (int g = 0; g < 4; g++) u[c][g] = *(const float4*)(rowp + g * 4);
    }

    float acc[16];
#pragma unroll
    for (int e = 0; e < 16; e++) acc[e] = 0.f;

#pragma unroll
    for (int c = 0; c < CC; c++) {
        const float* f = (const float*)&u[c][0];
        float mx = f[0];
#pragma unroll
        for (int e = 1; e < 16; e++) mx = fmaxf(mx, f[e]);
#pragma unroll
        for (int off = 1; off < 64; off <<= 1) mx = fmaxf(mx, __shfl_xor(mx, off));
        float sm = 0.f;
        float pe[16];
#pragma unroll
        for (int e = 0; e < 16; e++) { pe[e] = expf(f[e] - mx); sm += pe[e]; }
#pragma unroll
        for (int off = 1; off < 64; off <<= 1) sm += __shfl_xor(sm, off);
        if (lane == 0) ml[(size_t)(b * CC + c) * NN + n] = make_float2(mx, sm);
        float inv = 1.0f / sm;
#pragma unroll
        for (int e = 0; e < 16; e++) acc[e] += pe[e] * inv;
    }

    // per-wave threshold-select top-16 (R5-proven logic, values <= 8.0)
    unsigned vb[16];
#pragma unroll
    for (int e = 0; e < 16; e++) vb[e] = __float_as_uint(acc[e]);
    unsigned lo = 0u, hi = 0x41000000u;   // 8.0f: channel-sum of probs <= 8
    while (lo < hi) {
        unsigned mid = lo + ((hi - lo) >> 1);
        int c = 0;
#pragma unroll
        for (int e = 0; e < 16; e++)
            c += (int)__popcll(__ballot(vb[e] > mid));
        if (c <= 15) hi = mid; else lo = mid + 1;
    }
    const unsigned V = hi;
    int cgt = 0, ceq = 0;
#pragma unroll
    for (int e = 0; e < 16; e++) {
        cgt += (vb[e] > V) ? 1 : 0;
        ceq += (vb[e] == V) ? 1 : 0;
    }
    // packed wave prefix (gt in low 16 bits, eq in high 16)
    int pk = cgt | (ceq << 16);
    int incl = pk;
#pragma unroll
    for (int o = 1; o < 64; o <<= 1) {
        int v2 = __shfl_up(incl, o);
        if (lane >= o) incl += v2;
    }
    int tot = __shfl(incl, 63);
    int c1 = tot & 0xffff;          // total strictly-greater
    int need = KNBR - c1;           // ties to take (lowest index first)
    int excl = incl - pk;
    int pg = excl & 0xffff;
    int pe2 = excl >> 16;
    int lg = 0, le = 0;
#pragma unroll
    for (int e = 0; e < 16; e++) {
        if (vb[e] > V) {
            fsel[w][pg + lg] = colb + e; lg++;
        } else if (vb[e] == V) {
            if (pe2 + le < need) fsel[w][c1 + pe2 + le] = colb + e;
            le++;
        }
    }
    int fc = 0;
    if (lane == 0) {
        bool has = false;
#pragma unroll
        for (int t2 = 0; t2 < KNBR; t2++)
            if (fsel[w][t2] == n) has = true;
        fc = KNBR;
        if (!has) { fsel[w][KNBR] = n; fc = KNBR + 1; }
        cnt[bn] = fc;
    }
    fc = __shfl(fc, 0);
    if (lane < fc) {
        int k = fsel[w][lane];
        idx[bn * MAXSEL + lane] = k;
        atomicAdd(&countb[b * NN + k], 1);
    }
}

// ---------------------------------------------------------------------------
// Kernel 4: per b: exclusive prefix scan of countb -> offb; init single-copy
// curs.
// ---------------------------------------------------------------------------
__global__ __launch_bounds__(256) void scan_offb(const int* __restrict__ countb,
                                                 int* __restrict__ offb,
                                                 int* __restrict__ curs) {
    __shared__ int wtot[4];
    const int b = blockIdx.x, tid = threadIdx.x, lane = tid & 63, w = tid >> 6;
    int c0 = countb[b * NN + tid * 4 + 0];
    int c1 = countb[b * NN + tid * 4 + 1];
    int c2 = countb[b * NN + tid * 4 + 2];
    int c3 = countb[b * NN + tid * 4 + 3];
    int tsum = c0 + c1 + c2 + c3;
    int incl = tsum;
#pragma unroll
    for (int off = 1; off < 64; off <<= 1) {
        int v = __shfl_up(incl, off);
        if (lane >= off) incl += v;
    }
    if (lane == 63) wtot[w] = incl;
    __syncthreads();
    int woff = 0;
    for (int i = 0; i < w; i++) woff += wtot[i];
    int base = woff + incl - tsum;
    int o0 = base, o1 = base + c0, o2 = base + c0 + c1, o3 = base + c0 + c1 + c2;
    offb[b * NN + tid * 4 + 0] = o0;
    offb[b * NN + tid * 4 + 1] = o1;
    offb[b * NN + tid * 4 + 2] = o2;
    offb[b * NN + tid * 4 + 3] = o3;
    curs[b * NN + tid * 4 + 0] = o0;
    curs[b * NN + tid * 4 + 1] = o1;
    curs[b * NN + tid * 4 + 2] = o2;
    curs[b * NN + tid * 4 + 3] = o3;
}

// ---------------------------------------------------------------------------
// Kernel 4b: build the per-b CSR structure shared by all 8 channels:
// eidx16 (ushort m-list) and pmap[(b,n),j] -> entry position. Grid 64x64
// (one thread per row). Column visit order rotated per row ((jj+(n&15))
// mod c_, a bijection) to spread hub-column atomic contention.
// ---------------------------------------------------------------------------
__global__ __launch_bounds__(64) void fill_struct(const int* __restrict__ cnt,
                                                  const int* __restrict__ idx,
                                                  int* __restrict__ curs,
                                                  unsigned short* __restrict__ eidx16,
                                                  int* __restrict__ pmap) {
    const int b = blockIdx.x >> 4;
    const int n = ((blockIdx.x & 15) << 6) + threadIdx.x;
    const int bn = b * NN + n;
    const int c_ = cnt[bn];
    const int start = n & 15;   // < 16 <= c_
    for (int jj = 0; jj < MAXSEL; jj++) {
        if (jj < c_) {
            int j = jj + start;
            if (j >= c_) j -= c_;
            int k = idx[bn * MAXSEL + j];
            int p = atomicAdd(&curs[b * NN + k], 1);
            eidx16[b * ZCAP + p] = (unsigned short)n;
            pmap[bn * MAXSEL + j] = p;
        }
    }
}

// ---------------------------------------------------------------------------
// Kernel 5: per (z,n) thread: recompute 17 masked probs from raw logits +
// (max,denom); row-normalize; accumulate colsum; write fp16 value into the
// channel-major CSR slot eval8h[p][c] (position p from the shared structure).
// ---------------------------------------------------------------------------
__global__ __launch_bounds__(256) void rownorm_fill(const float* __restrict__ attn,
                                                    const float2* __restrict__ ml,
                                                    const int* __restrict__ idx,
                                                    const int* __restrict__ cnt,
                                                    const int* __restrict__ pmap,
                                                    float* __restrict__ nr,
                                                    float* __restrict__ colsum,
                                                    _Float16* __restrict__ eval8h) {
    const int t = blockIdx.x * 256 + threadIdx.x;  // z*N + n
    const int z = t >> 10, n = t & 1023;
    const int b = z >> 3, c = z & 7;
    const int bn = b * NN + n;
    const int c_ = cnt[bn];
    const float* arow = attn + (size_t)t * NN;
    const float2 MM = ml[t];
    const float invl = 1.0f / MM.y;
    float a[MAXSEL];
    int kk[MAXSEL];
    float s = 0.f;
#pragma unroll
    for (int j = 0; j < MAXSEL; j++) {
        if (j < c_) {
            kk[j] = idx[bn * MAXSEL + j];
            float p = expf(arow[kk[j]] - MM.x) * invl;
            a[j] = p; s += p;
        }
    }
    const float inv = 1.f / (s + 1e-6f);
#pragma unroll
    for (int j = 0; j < MAXSEL; j++) {
        if (j < c_) {
            float v = a[j] * inv;
            nr[(size_t)t * MAXSEL + j] = v;
            atomicAdd(&colsum[(size_t)z * NN + kk[j]], v);
            int p = pmap[bn * MAXSEL + j];
            eval8h[((size_t)b * ZCAP + p) * 8 + c] = (_Float16)v;
        }
    }
}

// ---------------------------------------------------------------------------
// Kernel 6: 8-CHANNEL-FUSED gather with ds_pk_add_f16 accumulation (R10:
// halved DS instr vs f32 atomics; each accumulator receives <= 17 adds so
// fp16 accumulation error ~5e-4). Layout accP[m*5+p] (stride 5, coprime 32).
// ---------------------------------------------------------------------------
__global__ __launch_bounds__(512) void out_sparse(const float* __restrict__ nr,
                                                  const int* __restrict__ idx,
                                                  const int* __restrict__ cnt,
                                                  const int* __restrict__ offb,
                                                  const int* __restrict__ countb,
                                                  const float* __restrict__ colsum,
                                                  const unsigned short* __restrict__ eidx16,
                                                  const _Float16* __restrict__ eval8h,
                                                  float* __restrict__ out) {
    __shared__ unsigned accP[NN * 5];    // 20 KB: channel-pair p of row m at m*5+p
    __shared__ float scm[CC][MAXSEL];
    __shared__ int goffs[MAXSEL];
    __shared__ int glens[MAXSEL];
    const int bn = blockIdx.x;           // b*NN + n
    const int b = bn >> 10, n = bn & 1023;
    const int tid = threadIdx.x, lane = tid & 63, w = tid >> 6;
    const int c_ = cnt[bn];

    // zero accP: 5120 words / 512 threads = 10 each
#pragma unroll
    for (int q = 0; q < 10; q++) accP[tid + q * 512] = 0u;

    // metadata: tid<256 -> scm[c][j]; tid in [256,273) -> off/len
    if (tid < 256) {
        int c = tid >> 5, j = tid & 31;
        if (j < MAXSEL) {
            float sc = 0.f;
            if (j < c_) {
                int z = b * CC + c;
                int k = idx[bn * MAXSEL + j];
                float wgt = nr[((size_t)z * NN + n) * MAXSEL + j];
                sc = wgt / (colsum[(size_t)z * NN + k] + 1e-6f);
            }
            scm[c][j] = sc;
        }
    } else if (tid < 256 + MAXSEL) {
        int j = tid - 256;
        int off = 0, len = 0;
        if (j < c_) {
            int k = idx[bn * MAXSEL + j];
            off = offb[b * NN + k];
            len = countb[b * NN + k];
        }
        goffs[j] = off; glens[j] = len;
    }
    __syncthreads();

    // gather: wave w takes columns w, w+8, ... ; 64 lanes over the slice
    for (int j = w; j < c_; j += 8) {
        const int off = goffs[j], len = glens[j];
        f16x8_t scv;
#pragma unroll
        for (int c = 0; c < 8; c++) scv[c] = (_Float16)scm[c][j];
        for (int l = lane; l < len; l += 64) {
            int m = eidx16[b * ZCAP + off + l];
            f16x8_t vh = *(const f16x8_t*)(eval8h + ((size_t)b * ZCAP + off + l) * 8);
            f16x8_t pr = vh * scv;               // 4x v_pk_mul_f16
            const unsigned* pw = (const unsigned*)&pr;
            unsigned base = (unsigned)(uintptr_t)&accP[m * 5];
            asm volatile("ds_pk_add_f16 %0, %1"           :: "v"(base), "v"(pw[0]) : "memory");
            asm volatile("ds_pk_add_f16 %0, %1 offset:4"  :: "v"(base), "v"(pw[1]) : "memory");
            asm volatile("ds_pk_add_f16 %0, %1 offset:8"  :: "v"(base), "v"(pw[2]) : "memory");
            asm volatile("ds_pk_add_f16 %0, %1 offset:12" :: "v"(base), "v"(pw[3]) : "memory");
        }
    }
    __syncthreads();

    // unpack + write 8 output rows (one per channel): 2048 float4 by 512 thr
#pragma unroll
    for (int q = 0; q < 4; q++) {
        int i4 = tid + q * 512;
        int c = i4 >> 8, m0 = (i4 & 255) * 4;
        int p = c >> 1, hi = c & 1;
        float4 vo;
        float* vp = (float*)&vo;
#pragma unroll
        for (int e = 0; e < 4; e++) {
            unsigned wrd = accP[(m0 + e) * 5 + p];
            f16x2_t h2 = *(const f16x2_t*)&wrd;
            vp[e] = (float)h2[hi];
        }
        *(float4*)(out + ((size_t)(b * CC + c) * NN + n) * NN + m0) = vo;
    }
}

// ---------------------------------------------------------------------------
extern "C" void kernel_launch(void* const* d_in, const int* in_sizes, int n_in,
                              void* d_out, int out_size, void* d_ws, size_t ws_size,
                              hipStream_t stream) {
    const float* x = (const float*)d_in[0];    // [4,1024,256]
    const float* W = (const float*)d_in[1];    // [256,4096]
    float* out = (float*)d_out;                // [4,8,1024,1024]
    char* ws = (char*)d_ws;

    // attn (raw logits*scale) lives in d_out; dead before out_sparse writes.
    float* attn = (float*)d_out;

    // workspace layout (bytes)
    _Float16* qh  = (_Float16*)(ws);                    // 16 MB each
    _Float16* ql  = (_Float16*)(ws + 16777216ull);
    _Float16* kh  = (_Float16*)(ws + 33554432ull);
    _Float16* kl  = (_Float16*)(ws + 50331648ull);
    _Float16* xh  = (_Float16*)(ws + 67108864ull);      // 2 MB each
    _Float16* xl  = (_Float16*)(ws + 69206016ull);
    _Float16* wth = (_Float16*)(ws + 71303168ull);
    _Float16* wtl = (_Float16*)(ws + 73400320ull);
    int*    idx  = (int*)   (ws + 75497472ull);   // 278,528
    int*    cnt  = (int*)   (ws + 75776000ull);   // 16,384
    float*  nr   = (float*) (ws + 75792384ull);   // 2,228,224
    float*  colsum = (float*)(ws + 78020608ull);  // 131,072
    float2* ml   = (float2*)(ws + 78151680ull);   // 262,144
    int*    countb = (int*) (ws + 78413824ull);   // 16,384
    int*    offb = (int*)   (ws + 78430208ull);   // 16,384
    int*    curs = (int*)   (ws + 78446592ull);   // 16,384
    unsigned short* eidx16 = (unsigned short*)(ws + 78462976ull); // 139,264
    _Float16* eval8h = (_Float16*)(ws + 78602240ull);             // 1,114,112
    int*    pmap = (int*)   (ws + 79716352ull);   // 278,528

    split_all<<<1280, 256, 0, stream>>>(x, W, xh, xl, wth, wtl, countb);
    gemm_xw_mfma<<<dim3(32, 32), 256, 0, stream>>>(xh, xl, wth, wtl,
                                                   qh, ql, kh, kl);
    gemm_qkt_mfma<<<2048, 256, 0, stream>>>(qh, ql, kh, kl, attn);
    softmax_topk<<<1024, 256, 0, stream>>>(attn, ml, idx, cnt, countb, colsum);
    scan_offb<<<4, 256, 0, stream>>>(countb, offb, curs);
    fill_struct<<<64, 64, 0, stream>>>(cnt, idx, curs, eidx16, pmap);
    rownorm_fill<<<128, 256, 0, stream>>>(attn, ml, idx, cnt, pmap, nr, colsum,
                                          eval8h);
    out_sparse<<<4096, 512, 0, stream>>>(nr, idx, cnt, offb, countb, colsum,
                                         eidx16, eval8h, out);
}

// Round 13
// 359.188 us; speedup vs baseline: 1.0074x; 1.0074x over previous
//
#include <hip/hip_runtime.h>
#include <hip/hip_bf16.h>
#include <math.h>

// Problem constants
#define BB 4
#define NN 1024
#define DD 256
#define CC 8
#define KNBR 16
#define MAXSEL 17   // 16 top-k + possibly the diagonal
#define ZCAP (NN * MAXSEL)   // 17408 max CSR entries per b (structure shared by 8 channels)

typedef _Float16 f16x8_t __attribute__((ext_vector_type(8)));
typedef _Float16 f16x4_t __attribute__((ext_vector_type(4)));
typedef _Float16 f16x2_t __attribute__((ext_vector_type(2)));
typedef float    f32x4_t __attribute__((ext_vector_type(4)));

// async global->LDS, 16 bytes per lane. ldsbase must be wave-uniform
// (HW places lane i at ldsbase + i*16).
__device__ __forceinline__ void gl2lds16(const _Float16* g, _Float16* ldsbase) {
    __builtin_amdgcn_global_load_lds(
        (const __attribute__((address_space(1))) unsigned int*)g,
        (__attribute__((address_space(3))) unsigned int*)ldsbase, 16, 0, 0);
}

// 2-level fp16 split: v = h + l + eps, |eps| <= ~2^-23 |v|
__device__ __forceinline__ void split2(float v, _Float16& h, _Float16& l) {
    h = (_Float16)v;
    l = (_Float16)(v - (float)h);
}

// ---------------------------------------------------------------------------
// Kernel 0: fused input prep. Blocks 0..1023: split x (fp16 h+l).
// Blocks 1024..1279: transpose + split 16*W (scale keeps residuals out of
// fp16 subnormal range; compensated by qkt scale /256).
// Block 1024 also zeroes countb.
// ---------------------------------------------------------------------------
__global__ __launch_bounds__(256) void split_all(const float* __restrict__ x,
                                                 const float* __restrict__ W,
                                                 _Float16* __restrict__ xh,
                                                 _Float16* __restrict__ xl,
                                                 _Float16* __restrict__ Wth,
                                                 _Float16* __restrict__ Wtl,
                                                 int* __restrict__ countb) {
    const int tid = threadIdx.x;
    if (blockIdx.x < 1024) {
        int i = (blockIdx.x * 256 + tid) * 4;
        float4 v = *(const float4*)(x + i);
        f16x4_t hv, lv;
        _Float16 h, l;
        split2(v.x, h, l); hv[0] = h; lv[0] = l;
        split2(v.y, h, l); hv[1] = h; lv[1] = l;
        split2(v.z, h, l); hv[2] = h; lv[2] = l;
        split2(v.w, h, l); hv[3] = h; lv[3] = l;
        *(f16x4_t*)(xh + i) = hv;
        *(f16x4_t*)(xl + i) = lv;
    } else {
        const int b2 = blockIdx.x - 1024;
        if (b2 == 0) {
            int4 zz = make_int4(0, 0, 0, 0);
#pragma unroll
            for (int g = 0; g < 4; g++) ((int4*)countb)[tid + 256 * g] = zz;
        }
        __shared__ float t[64][65];
        const int n0 = (b2 & 63) * 64;
        const int k0 = (b2 >> 6) * 64;
#pragma unroll
        for (int i = 0; i < 16; i++) {
            int k = i * 4 + (tid >> 6);
            int n = tid & 63;
            t[k][n] = W[(size_t)(k0 + k) * 4096 + n0 + n];
        }
        __syncthreads();
#pragma unroll
        for (int i = 0; i < 16; i++) {
            int n = i * 4 + (tid >> 6);
            int k = tid & 63;
            _Float16 h, l;
            split2(t[k][n] * 16.f, h, l);
            size_t o = (size_t)(n0 + n) * 256 + k0 + k;
            Wth[o] = h; Wtl[o] = l;
        }
    }
}

// stage one 128x32 fp16 tile (see R1 swizzle comment).
#define STG(dst, src, rowbase, kk)                                             \
    do {                                                                       \
        gl2lds16((src) + (size_t)((rowbase) + r_st) * 256 + (kk) + c8,         \
                 &(dst)[(w * 64) * 8]);                                        \
        gl2lds16((src) + (size_t)((rowbase) + 64 + r_st) * 256 + (kk) + c8,    \
                 &(dst)[(256 + w * 64) * 8]);                                  \
    } while (0)

// 3-term product ladder (hh last). (ah+al)(bh+bl) ~ al*bh + ah*bl + ah*bh
#define MFMA3(accv, AH, AL, BH, BL)                                            \
    do {                                                                       \
        accv = __builtin_amdgcn_mfma_f32_16x16x32_f16(AL, BH, accv, 0, 0, 0);  \
        accv = __builtin_amdgcn_mfma_f32_16x16x32_f16(AH, BL, accv, 0, 0, 0);  \
        accv = __builtin_amdgcn_mfma_f32_16x16x32_f16(AH, BH, accv, 0, 0, 0);  \
    } while (0)

// fragment loads + MFMA for one staged K=32 tile set
#define COMPUTE(AH, AL, BH, BL)                                                \
    do {                                                                       \
        f16x8_t ah[4], al[4];                                                  \
        _Pragma("unroll")                                                      \
        for (int mi = 0; mi < 4; mi++) {                                       \
            int r = (wr * 64 + mi * 16 + lm) * 32 + qx8;                       \
            ah[mi] = *(const f16x8_t*)&(AH)[r];                                \
            al[mi] = *(const f16x8_t*)&(AL)[r];                                \
        }                                                                      \
        _Pragma("unroll")                                                      \
        for (int ni = 0; ni < 4; ni++) {                                       \
            int rb = (wc * 64 + ni * 16 + lm) * 32 + qx8;                      \
            f16x8_t bh = *(const f16x8_t*)&(BH)[rb];                           \
            f16x8_t bl = *(const f16x8_t*)&(BL)[rb];                           \
            _Pragma("unroll")                                                  \
            for (int mi = 0; mi < 4; mi++)                                     \
                MFMA3(acc[mi][ni], ah[mi], al[mi], bh, bl);                    \
        }                                                                      \
    } while (0)

// ---------------------------------------------------------------------------
// Kernel 1: qk = x @ (16W) via 3-term fp16x2 MFMA, double-buffered LDS with
// next-tile prefetch (one barrier per K-iter); LDS-transpose epilogue with
// coalesced fp16x8 stores of the 2-split q/k components.
// ---------------------------------------------------------------------------
__global__ __launch_bounds__(256) void gemm_xw_mfma(
        const _Float16* __restrict__ xh, const _Float16* __restrict__ xl,
        const _Float16* __restrict__ wth, const _Float16* __restrict__ wtl,
        _Float16* __restrict__ qh, _Float16* __restrict__ ql,
        _Float16* __restrict__ kh, _Float16* __restrict__ kl) {
    __shared__ __align__(16) char smem[65536];
    _Float16* Ah0 = (_Float16*)smem;
    _Float16* Al0 = (_Float16*)(smem + 8192);
    _Float16* Bh0 = (_Float16*)(smem + 16384);
    _Float16* Bl0 = (_Float16*)(smem + 24576);
    _Float16* Ah1 = (_Float16*)(smem + 32768);
    _Float16* Al1 = (_Float16*)(smem + 40960);
    _Float16* Bh1 = (_Float16*)(smem + 49152);
    _Float16* Bl1 = (_Float16*)(smem + 57344);
    const int tid = threadIdx.x, lane = tid & 63, w = tid >> 6;
    const int wr = w >> 1, wc = w & 1;
    const int lm = lane & 15, quad = lane >> 4;
    const int row0 = blockIdx.y * 128, col0 = blockIdx.x * 128;
    const int r_st = tid >> 2;
    const int c8 = (((tid & 3) ^ ((tid >> 3) & 3)) * 8);
    const int qx8 = ((quad ^ ((lm >> 1) & 3)) * 8);

    f32x4_t acc[4][4];
#pragma unroll
    for (int i = 0; i < 4; i++)
#pragma unroll
        for (int j = 0; j < 4; j++) acc[i][j] = (f32x4_t)(0.f);

    STG(Ah0, xh, row0, 0); STG(Al0, xl, row0, 0);
    STG(Bh0, wth, col0, 0); STG(Bl0, wtl, col0, 0);
    __syncthreads();
#pragma unroll
    for (int t = 0; t < 8; t += 2) {
        {
            int kn = (t + 1) * 32;
            if (t + 1 < 8) {
                STG(Ah1, xh, row0, kn); STG(Al1, xl, row0, kn);
                STG(Bh1, wth, col0, kn); STG(Bl1, wtl, col0, kn);
            }
            COMPUTE(Ah0, Al0, Bh0, Bl0);
            __syncthreads();
        }
        {
            int kn = (t + 2) * 32;
            if (t + 2 < 8) {
                STG(Ah0, xh, row0, kn); STG(Al0, xl, row0, kn);
                STG(Bh0, wth, col0, kn); STG(Bl0, wtl, col0, kn);
            }
            COMPUTE(Ah1, Al1, Bh1, Bl1);
            __syncthreads();
        }
    }

    // Epilogue: two 64-row passes through LDS (fp32, stride 132 = bank-safe),
    // then coalesced fp16x8 stores of the 2 split components.
    float* tr = (float*)smem;   // 64 x 132 fp32 = 33792 B
    const int s = col0 >> 11, c = (col0 >> 8) & 7, dbase = col0 & 255;
    _Float16* dh = s ? kh : qh;
    _Float16* dl = s ? kl : ql;
    const int rl = tid >> 2;
    const int cb = (tid & 3) * 8;
#pragma unroll
    for (int p = 0; p < 2; p++) {
        if (p) __syncthreads();
        if (wr == p) {
#pragma unroll
            for (int mi = 0; mi < 4; mi++) {
                int rloc = mi * 16 + quad * 4;
#pragma unroll
                for (int ni = 0; ni < 4; ni++) {
                    int cl = wc * 64 + ni * 16 + lm;
#pragma unroll
                    for (int r = 0; r < 4; r++)
                        tr[(rloc + r) * 132 + cl] = acc[mi][ni][r];
                }
            }
        }
        __syncthreads();
        int rr = row0 + p * 64 + rl;
        int bb = rr >> 10, n = rr & 1023;
        size_t base = (((size_t)(bb * CC + c)) * NN + n) * DD + dbase;
#pragma unroll
        for (int g = 0; g < 4; g++) {
            int ccol = g * 32 + cb;
            f16x8_t hv, lv;
#pragma unroll
            for (int e = 0; e < 8; e++) {
                float vv = tr[rl * 132 + ccol + e];
                _Float16 h, l;
                split2(vv, h, l);
                hv[e] = h; lv[e] = l;
            }
            *(f16x8_t*)(dh + base + ccol) = hv;
            *(f16x8_t*)(dl + base + ccol) = lv;
        }
    }
}

// ---------------------------------------------------------------------------
// Kernel 2: per z: attn = (q @ k^T) * scale via 3-term fp16x2 MFMA, f32
// output (R12 fp16-attn REVERTED: top-k selection is discontinuous in its
// inputs; fp16 logits flipped near-tied selections -> absmax 0.19).
// scale = 0.0625/256 (q,k carry 16x each from 16W).
// ---------------------------------------------------------------------------
__global__ __launch_bounds__(256) void gemm_qkt_mfma(
        const _Float16* __restrict__ qh, const _Float16* __restrict__ ql,
        const _Float16* __restrict__ kh, const _Float16* __restrict__ kl,
        float* __restrict__ attn) {
    __shared__ __align__(16) char smem[65536];
    _Float16* Ah0 = (_Float16*)smem;
    _Float16* Al0 = (_Float16*)(smem + 8192);
    _Float16* Bh0 = (_Float16*)(smem + 16384);
    _Float16* Bl0 = (_Float16*)(smem + 24576);
    _Float16* Ah1 = (_Float16*)(smem + 32768);
    _Float16* Al1 = (_Float16*)(smem + 40960);
    _Float16* Bh1 = (_Float16*)(smem + 49152);
    _Float16* Bl1 = (_Float16*)(smem + 57344);
    const int tid = threadIdx.x, lane = tid & 63, w = tid >> 6;
    const int wr = w >> 1, wc = w & 1;
    const int lm = lane & 15, quad = lane >> 4;
    const int id = blockIdx.x;
    const int rb8 = id & 7, qq = id >> 3;
    const int j = qq & 63, zhi = qq >> 6;
    const int z = zhi * 8 + rb8;
    const int row0 = (j >> 3) * 128, col0 = (j & 7) * 128;
    const size_t zo = (size_t)z * NN * DD;
    float* Cm = attn + (size_t)z * NN * NN;
    const int r_st = tid >> 2;
    const int c8 = (((tid & 3) ^ ((tid >> 3) & 3)) * 8);
    const int qx8 = ((quad ^ ((lm >> 1) & 3)) * 8);
    const float scale = 0.0625f / 256.0f;

    f32x4_t acc[4][4];
#pragma unroll
    for (int i = 0; i < 4; i++)
#pragma unroll
        for (int j2 = 0; j2 < 4; j2++) acc[i][j2] = (f32x4_t)(0.f);

    const _Float16* qhz = qh + zo;
    const _Float16* qlz = ql + zo;
    const _Float16* khz = kh + zo;
    const _Float16* klz = kl + zo;

    STG(Ah0, qhz, row0, 0); STG(Al0, qlz, row0, 0);
    STG(Bh0, khz, col0, 0); STG(Bl0, klz, col0, 0);
    __syncthreads();
#pragma unroll
    for (int t = 0; t < 8; t += 2) {
        {
            int kn = (t + 1) * 32;
            if (t + 1 < 8) {
                STG(Ah1, qhz, row0, kn); STG(Al1, qlz, row0, kn);
                STG(Bh1, khz, col0, kn); STG(Bl1, klz, col0, kn);
            }
            COMPUTE(Ah0, Al0, Bh0, Bl0);
            __syncthreads();
        }
        {
            int kn = (t + 2) * 32;
            if (t + 2 < 8) {
                STG(Ah0, qhz, row0, kn); STG(Al0, qlz, row0, kn);
                STG(Bh0, khz, col0, kn); STG(Bl0, klz, col0, kn);
            }
            COMPUTE(Ah1, Al1, Bh1, Bl1);
            __syncthreads();
        }
    }

#pragma unroll
    for (int mi = 0; mi < 4; mi++)
#pragma unroll
        for (int ni = 0; ni < 4; ni++) {
            int row = row0 + wr * 64 + mi * 16 + quad * 4;
            int col = col0 + wc * 64 + ni * 16 + lm;
#pragma unroll
            for (int r = 0; r < 4; r++)
                Cm[(size_t)(row + r) * NN + col] = acc[mi][ni][r] * scale;
        }
}

// ---------------------------------------------------------------------------
// Kernel 3: ONE ROW PER WAVE softmax+topk (R10 structure, f32 attn). Each
// wave owns one (b,n): loads all 8 channels' 16-col slices upfront, stats
// per channel via shfl_xor butterflies, channel-sum in registers; per-wave
// threshold-select top-16 (R5-proven logic).
// ---------------------------------------------------------------------------
__global__ __launch_bounds__(256) void softmax_topk(const float* __restrict__ attn,
                                                    float2* __restrict__ ml,
                                                    int* __restrict__ idx,
                                                    int* __restrict__ cnt,
                                                    int* __restrict__ countb,
                                                    float* __restrict__ colsum) {
    __shared__ int fsel[4][MAXSEL];
    const int tid = threadIdx.x, lane = tid & 63, w = tid >> 6;
    const int bn = blockIdx.x * 4 + w;   // one row per wave
    const int b = bn >> 10, n = bn & 1023;

    if (lane < CC) colsum[(size_t)(b * CC + lane) * NN + n] = 0.f;

    const int colb = lane * 16;
    // all 8 channels loaded upfront: 32 float4 loads in flight, one latency
    float4 u[CC][4];
#pragma unroll
    for (int c = 0; c < CC; c++) {
        const float* rowp = attn + (((size_t)(b * CC + c) * NN + n) * NN) + colb;
#pragma unroll
        for (int g = 0; g < 4; g++) u[c][g] = *(const float4*)(rowp + g * 4);
    }

    float acc[16];
#pragma unroll
    for (int e = 0; e < 16; e++) acc[e] = 0.f;

#pragma unroll
    for (int c = 0; c < CC; c++) {
        const float* f = (const float*)&u[c][0];
        float mx = f[0];
#pragma unroll
        for (int e = 1; e < 16; e++) mx = fmaxf(mx, f[e]);
#pragma unroll
        for (int off = 1; off < 64; off <<= 1) mx = fmaxf(mx, __shfl_xor(mx, off));
        float sm = 0.f;
        float pe[16];
#pragma unroll
        for (int e = 0; e < 16; e++) { pe[e] = expf(f[e] - mx); sm += pe[e]; }
#pragma unroll
        for (int off = 1; off < 64; off <<= 1) sm += __shfl_xor(sm, off);
        if (lane == 0) ml[(size_t)(b * CC + c) * NN + n] = make_float2(mx, sm);
        float inv = 1.0f / sm;
#pragma unroll
        for (int e = 0; e < 16; e++) acc[e] += pe[e] * inv;
    }

    // per-wave threshold-select top-16 (R5-proven logic, values <= 8.0)
    unsigned vb[16];
#pragma unroll
    for (int e = 0; e < 16; e++) vb[e] = __float_as_uint(acc[e]);
    unsigned lo = 0u, hi = 0x41000000u;   // 8.0f: channel-sum of probs <= 8
    while (lo < hi) {
        unsigned mid = lo + ((hi - lo) >> 1);
        int c = 0;
#pragma unroll
        for (int e = 0; e < 16; e++)
            c += (int)__popcll(__ballot(vb[e] > mid));
        if (c <= 15) hi = mid; else lo = mid + 1;
    }
    const unsigned V = hi;
    int cgt = 0, ceq = 0;
#pragma unroll
    for (int e = 0; e < 16; e++) {
        cgt += (vb[e] > V) ? 1 : 0;
        ceq += (vb[e] == V) ? 1 : 0;
    }
    // packed wave prefix (gt in low 16 bits, eq in high 16)
    int pk = cgt | (ceq << 16);
    int incl = pk;
#pragma unroll
    for (int o = 1; o < 64; o <<= 1) {
        int v2 = __shfl_up(incl, o);
        if (lane >= o) incl += v2;
    }
    int tot = __shfl(incl, 63);
    int c1 = tot & 0xffff;          // total strictly-greater
    int need = KNBR - c1;           // ties to take (lowest index first)
    int excl = incl - pk;
    int pg = excl & 0xffff;
    int pe2 = excl >> 16;
    int lg = 0, le = 0;
#pragma unroll
    for (int e = 0; e < 16; e++) {
        if (vb[e] > V) {
            fsel[w][pg + lg] = colb + e; lg++;
        } else if (vb[e] == V) {
            if (pe2 + le < need) fsel[w][c1 + pe2 + le] = colb + e;
            le++;
        }
    }
    int fc = 0;
    if (lane == 0) {
        bool has = false;
#pragma unroll
        for (int t2 = 0; t2 < KNBR; t2++)
            if (fsel[w][t2] == n) has = true;
        fc = KNBR;
        if (!has) { fsel[w][KNBR] = n; fc = KNBR + 1; }
        cnt[bn] = fc;
    }
    fc = __shfl(fc, 0);
    if (lane < fc) {
        int k = fsel[w][lane];
        idx[bn * MAXSEL + lane] = k;
        atomicAdd(&countb[b * NN + k], 1);
    }
}

// ---------------------------------------------------------------------------
// Kernel 4: per b: exclusive prefix scan of countb -> offb; init single-copy
// curs.
// ---------------------------------------------------------------------------
__global__ __launch_bounds__(256) void scan_offb(const int* __restrict__ countb,
                                                 int* __restrict__ offb,
                                                 int* __restrict__ curs) {
    __shared__ int wtot[4];
    const int b = blockIdx.x, tid = threadIdx.x, lane = tid & 63, w = tid >> 6;
    int c0 = countb[b * NN + tid * 4 + 0];
    int c1 = countb[b * NN + tid * 4 + 1];
    int c2 = countb[b * NN + tid * 4 + 2];
    int c3 = countb[b * NN + tid * 4 + 3];
    int tsum = c0 + c1 + c2 + c3;
    int incl = tsum;
#pragma unroll
    for (int off = 1; off < 64; off <<= 1) {
        int v = __shfl_up(incl, off);
        if (lane >= off) incl += v;
    }
    if (lane == 63) wtot[w] = incl;
    __syncthreads();
    int woff = 0;
    for (int i = 0; i < w; i++) woff += wtot[i];
    int base = woff + incl - tsum;
    int o0 = base, o1 = base + c0, o2 = base + c0 + c1, o3 = base + c0 + c1 + c2;
    offb[b * NN + tid * 4 + 0] = o0;
    offb[b * NN + tid * 4 + 1] = o1;
    offb[b * NN + tid * 4 + 2] = o2;
    offb[b * NN + tid * 4 + 3] = o3;
    curs[b * NN + tid * 4 + 0] = o0;
    curs[b * NN + tid * 4 + 1] = o1;
    curs[b * NN + tid * 4 + 2] = o2;
    curs[b * NN + tid * 4 + 3] = o3;
}

// ---------------------------------------------------------------------------
// Kernel 4b: build the per-b CSR structure shared by all 8 channels:
// eidx16 (ushort m-list) and pmap[(b,n),j] -> entry position. Grid 64x64
// (one thread per row). Column visit order rotated per row ((jj+(n&15))
// mod c_, a bijection) to spread hub-column atomic contention.
// ---------------------------------------------------------------------------
__global__ __launch_bounds__(64) void fill_struct(const int* __restrict__ cnt,
                                                  const int* __restrict__ idx,
                                                  int* __restrict__ curs,
                                                  unsigned short* __restrict__ eidx16,
                                                  int* __restrict__ pmap) {
    const int b = blockIdx.x >> 4;
    const int n = ((blockIdx.x & 15) << 6) + threadIdx.x;
    const int bn = b * NN + n;
    const int c_ = cnt[bn];
    const int start = n & 15;   // < 16 <= c_
    for (int jj = 0; jj < MAXSEL; jj++) {
        if (jj < c_) {
            int j = jj + start;
            if (j >= c_) j -= c_;
            int k = idx[bn * MAXSEL + j];
            int p = atomicAdd(&curs[b * NN + k], 1);
            eidx16[b * ZCAP + p] = (unsigned short)n;
            pmap[bn * MAXSEL + j] = p;
        }
    }
}

// ---------------------------------------------------------------------------
// Kernel 5: per (z,n) thread: recompute 17 masked probs from f32 logits +
// (max,denom); row-normalize; accumulate colsum; write fp16 value into the
// channel-major CSR slot eval8h[p][c] (position p from the shared structure).
// ---------------------------------------------------------------------------
__global__ __launch_bounds__(256) void rownorm_fill(const float* __restrict__ attn,
                                                    const float2* __restrict__ ml,
                                                    const int* __restrict__ idx,
                                                    const int* __restrict__ cnt,
                                                    const int* __restrict__ pmap,
                                                    float* __restrict__ nr,
                                                    float* __restrict__ colsum,
                                                    _Float16* __restrict__ eval8h) {
    const int t = blockIdx.x * 256 + threadIdx.x;  // z*N + n
    const int z = t >> 10, n = t & 1023;
    const int b = z >> 3, c = z & 7;
    const int bn = b * NN + n;
    const int c_ = cnt[bn];
    const float* arow = attn + (size_t)t * NN;
    const float2 MM = ml[t];
    const float invl = 1.0f / MM.y;
    float a[MAXSEL];
    int kk[MAXSEL];
    float s = 0.f;
#pragma unroll
    for (int j = 0; j < MAXSEL; j++) {
        if (j < c_) {
            kk[j] = idx[bn * MAXSEL + j];
            float p = expf(arow[kk[j]] - MM.x) * invl;
            a[j] = p; s += p;
        }
    }
    const float inv = 1.f / (s + 1e-6f);
#pragma unroll
    for (int j = 0; j < MAXSEL; j++) {
        if (j < c_) {
            float v = a[j] * inv;
            nr[(size_t)t * MAXSEL + j] = v;
            atomicAdd(&colsum[(size_t)z * NN + kk[j]], v);
            int p = pmap[bn * MAXSEL + j];
            eval8h[((size_t)b * ZCAP + p) * 8 + c] = (_Float16)v;
        }
    }
}

// ---------------------------------------------------------------------------
// Kernel 6: 8-CHANNEL-FUSED gather with ds_pk_add_f16 accumulation (R10:
// halved DS instr vs f32 atomics; each accumulator receives <= 17 adds so
// fp16 accumulation error ~5e-4). Layout accP[m*5+p] (stride 5, coprime 32).
// ---------------------------------------------------------------------------
__global__ __launch_bounds__(512) void out_sparse(const float* __restrict__ nr,
                                                  const int* __restrict__ idx,
                                                  const int* __restrict__ cnt,
                                                  const int* __restrict__ offb,
                                                  const int* __restrict__ countb,
                                                  const float* __restrict__ colsum,
                                                  const unsigned short* __restrict__ eidx16,
                                                  const _Float16* __restrict__ eval8h,
                                                  float* __restrict__ out) {
    __shared__ unsigned accP[NN * 5];    // 20 KB: channel-pair p of row m at m*5+p
    __shared__ float scm[CC][MAXSEL];
    __shared__ int goffs[MAXSEL];
    __shared__ int glens[MAXSEL];
    const int bn = blockIdx.x;           // b*NN + n
    const int b = bn >> 10, n = bn & 1023;
    const int tid = threadIdx.x, lane = tid & 63, w = tid >> 6;
    const int c_ = cnt[bn];

    // zero accP: 5120 words / 512 threads = 10 each
#pragma unroll
    for (int q = 0; q < 10; q++) accP[tid + q * 512] = 0u;

    // metadata: tid<256 -> scm[c][j]; tid in [256,273) -> off/len
    if (tid < 256) {
        int c = tid >> 5, j = tid & 31;
        if (j < MAXSEL) {
            float sc = 0.f;
            if (j < c_) {
                int z = b * CC + c;
                int k = idx[bn * MAXSEL + j];
                float wgt = nr[((size_t)z * NN + n) * MAXSEL + j];
                sc = wgt / (colsum[(size_t)z * NN + k] + 1e-6f);
            }
            scm[c][j] = sc;
        }
    } else if (tid < 256 + MAXSEL) {
        int j = tid - 256;
        int off = 0, len = 0;
        if (j < c_) {
            int k = idx[bn * MAXSEL + j];
            off = offb[b * NN + k];
            len = countb[b * NN + k];
        }
        goffs[j] = off; glens[j] = len;
    }
    __syncthreads();

    // gather: wave w takes columns w, w+8, ... ; 64 lanes over the slice
    for (int j = w; j < c_; j += 8) {
        const int off = goffs[j], len = glens[j];
        f16x8_t scv;
#pragma unroll
        for (int c = 0; c < 8; c++) scv[c] = (_Float16)scm[c][j];
        for (int l = lane; l < len; l += 64) {
            int m = eidx16[b * ZCAP + off + l];
            f16x8_t vh = *(const f16x8_t*)(eval8h + ((size_t)b * ZCAP + off + l) * 8);
            f16x8_t pr = vh * scv;               // 4x v_pk_mul_f16
            const unsigned* pw = (const unsigned*)&pr;
            unsigned base = (unsigned)(uintptr_t)&accP[m * 5];
            asm volatile("ds_pk_add_f16 %0, %1"           :: "v"(base), "v"(pw[0]) : "memory");
            asm volatile("ds_pk_add_f16 %0, %1 offset:4"  :: "v"(base), "v"(pw[1]) : "memory");
            asm volatile("ds_pk_add_f16 %0, %1 offset:8"  :: "v"(base), "v"(pw[2]) : "memory");
            asm volatile("ds_pk_add_f16 %0, %1 offset:12" :: "v"(base), "v"(pw[3]) : "memory");
        }
    }
    __syncthreads();

    // unpack + write 8 output rows (one per channel): 2048 float4 by 512 thr
#pragma unroll
    for (int q = 0; q < 4; q++) {
        int i4 = tid + q * 512;
        int c = i4 >> 8, m0 = (i4 & 255) * 4;
        int p = c >> 1, hi = c & 1;
        float4 vo;
        float* vp = (float*)&vo;
#pragma unroll
        for (int e = 0; e < 4; e++) {
            unsigned wrd = accP[(m0 + e) * 5 + p];
            f16x2_t h2 = *(const f16x2_t*)&wrd;
            vp[e] = (float)h2[hi];
        }
        *(float4*)(out + ((size_t)(b * CC + c) * NN + n) * NN + m0) = vo;
    }
}

// ---------------------------------------------------------------------------
extern "C" void kernel_launch(void* const* d_in, const int* in_sizes, int n_in,
                              void* d_out, int out_size, void* d_ws, size_t ws_size,
                              hipStream_t stream) {
    const float* x = (const float*)d_in[0];    // [4,1024,256]
    const float* W = (const float*)d_in[1];    // [256,4096]
    float* out = (float*)d_out;                // [4,8,1024,1024]
    char* ws = (char*)d_ws;

    // attn (f32 logits*scale) lives in d_out; dead before out_sparse writes.
    float* attn = (float*)d_out;

    // workspace layout (bytes)
    _Float16* qh  = (_Float16*)(ws);                    // 16 MB each
    _Float16* ql  = (_Float16*)(ws + 16777216ull);
    _Float16* kh  = (_Float16*)(ws + 33554432ull);
    _Float16* kl  = (_Float16*)(ws + 50331648ull);
    _Float16* xh  = (_Float16*)(ws + 67108864ull);      // 2 MB each
    _Float16* xl  = (_Float16*)(ws + 69206016ull);
    _Float16* wth = (_Float16*)(ws + 71303168ull);
    _Float16* wtl = (_Float16*)(ws + 73400320ull);
    int*    idx  = (int*)   (ws + 75497472ull);   // 278,528
    int*    cnt  = (int*)   (ws + 75776000ull);   // 16,384
    float*  nr   = (float*) (ws + 75792384ull);   // 2,228,224
    float*  colsum = (float*)(ws + 78020608ull);  // 131,072
    float2* ml   = (float2*)(ws + 78151680ull);   // 262,144
    int*    countb = (int*) (ws + 78413824ull);   // 16,384
    int*    offb = (int*)   (ws + 78430208ull);   // 16,384
    int*    curs = (int*)   (ws + 78446592ull);   // 16,384
    unsigned short* eidx16 = (unsigned short*)(ws + 78462976ull); // 139,264
    _Float16* eval8h = (_Float16*)(ws + 78602240ull);             // 1,114,112
    int*    pmap = (int*)   (ws + 79716352ull);   // 278,528

    split_all<<<1280, 256, 0, stream>>>(x, W, xh, xl, wth, wtl, countb);
    gemm_xw_mfma<<<dim3(32, 32), 256, 0, stream>>>(xh, xl, wth, wtl,
                                                   qh, ql, kh, kl);
    gemm_qkt_mfma<<<2048, 256, 0, stream>>>(qh, ql, kh, kl, attn);
    softmax_topk<<<1024, 256, 0, stream>>>(attn, ml, idx, cnt, countb, colsum);
    scan_offb<<<4, 256, 0, stream>>>(countb, offb, curs);
    fill_struct<<<64, 64, 0, stream>>>(cnt, idx, curs, eidx16, pmap);
    rownorm_fill<<<128, 256, 0, stream>>>(attn, ml, idx, cnt, pmap, nr, colsum,
                                          eval8h);
    out_sparse<<<4096, 512, 0, stream>>>(nr, idx, cnt, offb, countb, colsum,
                                         eidx16, eval8h, out);
}